// Round 1
// baseline (1635.637 us; speedup 1.0000x reference)
//
#include <hip/hip_runtime.h>

#define N_NODES   100000
#define N_EDGES   1600000
#define F         128
#define N_CLASSES 47

// ---------------- CSR build ----------------

__global__ void count_kernel(const int* __restrict__ dst, int* __restrict__ cnt) {
    int e = blockIdx.x * blockDim.x + threadIdx.x;
    if (e < N_EDGES) atomicAdd(&cnt[dst[e]], 1);
}

__global__ void scan_kernel(const int* __restrict__ cnt, int* __restrict__ row_ptr,
                            float* __restrict__ rdeg) {
    const int T = 1024;
    const int CHUNK = (N_NODES + T - 1) / T;  // 98
    __shared__ int sums[T];
    __shared__ int offs[T + 1];
    int t = threadIdx.x;
    int lo = t * CHUNK;
    int hi = min(lo + CHUNK, N_NODES);
    int s = 0;
    for (int i = lo; i < hi; ++i) s += cnt[i];
    sums[t] = s;
    __syncthreads();
    if (t == 0) {
        int acc = 0;
        for (int i = 0; i < T; ++i) { offs[i] = acc; acc += sums[i]; }
        offs[T] = acc;
    }
    __syncthreads();
    int acc = offs[t];
    for (int i = lo; i < hi; ++i) {
        row_ptr[i] = acc;
        int c = cnt[i];
        rdeg[i] = 1.0f / (float)max(c, 1);
        acc += c;
    }
    if (t == T - 1) row_ptr[N_NODES] = offs[T];
}

__global__ void fill_kernel(const int* __restrict__ src, const int* __restrict__ dst,
                            const int* __restrict__ row_ptr, int* __restrict__ fill,
                            int* __restrict__ col) {
    int e = blockIdx.x * blockDim.x + threadIdx.x;
    if (e < N_EDGES) {
        int d = dst[e];
        int p = row_ptr[d] + atomicAdd(&fill[d], 1);
        col[p] = src[e];
    }
}

// ---------------- embedding gather ----------------

__global__ void gather_embed_kernel(const float* __restrict__ embed,
                                    const int* __restrict__ idx,
                                    float* __restrict__ h) {
    int i = blockIdx.x * blockDim.x + threadIdx.x;   // one float4 per thread
    const int TOTAL = N_NODES * (F / 4);
    if (i < TOTAL) {
        int node = i / (F / 4);
        int c4 = i % (F / 4);
        const float4* s = (const float4*)(embed + (size_t)idx[node] * F);
        ((float4*)(h + (size_t)node * F))[c4] = s[c4];
    }
}

// ---------------- pull aggregation: mean over in-neighbors ----------------
// one wave (64 lanes) per node; lane handles 2 consecutive feats (float2)

__global__ void aggregate_kernel(const float* __restrict__ h,
                                 const int* __restrict__ row_ptr,
                                 const int* __restrict__ col,
                                 const float* __restrict__ rdeg,
                                 float* __restrict__ mean) {
    int wave = threadIdx.x >> 6;
    int lane = threadIdx.x & 63;
    int v = blockIdx.x * 4 + wave;
    if (v >= N_NODES) return;
    int beg = row_ptr[v], end = row_ptr[v + 1];
    float ax = 0.f, ay = 0.f;
    for (int p = beg; p < end; ++p) {
        int u = col[p];
        float2 x = *(const float2*)(h + (size_t)u * F + lane * 2);
        ax += x.x; ay += x.y;
    }
    float r = rdeg[v];
    float2 o; o.x = ax * r; o.y = ay * r;
    *(float2*)(mean + (size_t)v * F + lane * 2) = o;
}

// ---------------- fused GEMM: out = mean@Wn + h@Ws + b (+relu) ----------------
// block: 256 threads, 64 rows. A tiles (mean,h) staged in LDS.
// NPAD: padded column count (multiple of 4, 256 % (NPAD/4) == 0)

template<int NOUT, int NPAD, bool RELU>
__global__ __launch_bounds__(256)
void gemm_kernel(const float* __restrict__ mean, const float* __restrict__ h,
                 const float* __restrict__ Wn, const float* __restrict__ Ws,
                 const float* __restrict__ bias, float* __restrict__ out) {
    constexpr int BM  = 64;
    constexpr int CGP = NPAD / 4;     // col groups of 4
    constexpr int RS  = 256 / CGP;    // row slots
    constexpr int RPT = BM / RS;      // rows per thread
    constexpr int LDA = F + 4;        // 132 floats: 16B-aligned stride, conflict-free

    __shared__ float As[2][BM * LDA];

    const int t = threadIdx.x;
    const int row0 = blockIdx.x * BM;

    // stage A tiles (mean, h) -> LDS, float4 coalesced
    {
        const int NF4 = BM * (F / 4);   // 2048
        for (int i = t; i < NF4; i += 256) {
            int r  = i >> 5;
            int c4 = i & 31;
            int row = row0 + r;
            float4 m4 = make_float4(0.f, 0.f, 0.f, 0.f);
            float4 h4 = make_float4(0.f, 0.f, 0.f, 0.f);
            if (row < N_NODES) {
                m4 = ((const float4*)(mean + (size_t)row * F))[c4];
                h4 = ((const float4*)(h   + (size_t)row * F))[c4];
            }
            *((float4*)(&As[0][r * LDA + c4 * 4])) = m4;
            *((float4*)(&As[1][r * LDA + c4 * 4])) = h4;
        }
    }
    __syncthreads();

    const int cg = t % CGP;
    const int rs = t / CGP;
    const int c0 = cg * 4;

    float acc[RPT][4];
    #pragma unroll
    for (int i = 0; i < RPT; ++i)
        #pragma unroll
        for (int j = 0; j < 4; ++j) acc[i][j] = 0.f;

    #pragma unroll
    for (int ph = 0; ph < 2; ++ph) {
        const float* __restrict__ W = ph ? Ws : Wn;
        const float* __restrict__ A = &As[ph][0];
        #pragma unroll 4
        for (int k = 0; k < F; ++k) {
            float4 w;
            if (NOUT == NPAD) {
                w = ((const float4*)(W + (size_t)k * NOUT))[cg];
            } else {
                w.x = (c0 + 0 < NOUT) ? W[k * NOUT + c0 + 0] : 0.f;
                w.y = (c0 + 1 < NOUT) ? W[k * NOUT + c0 + 1] : 0.f;
                w.z = (c0 + 2 < NOUT) ? W[k * NOUT + c0 + 2] : 0.f;
                w.w = (c0 + 3 < NOUT) ? W[k * NOUT + c0 + 3] : 0.f;
            }
            #pragma unroll
            for (int i = 0; i < RPT; ++i) {
                float a = A[(rs * RPT + i) * LDA + k];
                acc[i][0] = fmaf(a, w.x, acc[i][0]);
                acc[i][1] = fmaf(a, w.y, acc[i][1]);
                acc[i][2] = fmaf(a, w.z, acc[i][2]);
                acc[i][3] = fmaf(a, w.w, acc[i][3]);
            }
        }
    }

    // epilogue: bias (+relu), store
    #pragma unroll
    for (int i = 0; i < RPT; ++i) {
        int row = row0 + rs * RPT + i;
        if (row >= N_NODES) continue;
        if (NOUT == NPAD) {
            float4 v;
            v.x = acc[i][0] + bias[c0 + 0];
            v.y = acc[i][1] + bias[c0 + 1];
            v.z = acc[i][2] + bias[c0 + 2];
            v.w = acc[i][3] + bias[c0 + 3];
            if (RELU) {
                v.x = fmaxf(v.x, 0.f); v.y = fmaxf(v.y, 0.f);
                v.z = fmaxf(v.z, 0.f); v.w = fmaxf(v.w, 0.f);
            }
            ((float4*)(out + (size_t)row * NOUT))[cg] = v;
        } else {
            #pragma unroll
            for (int j = 0; j < 4; ++j) {
                int c = c0 + j;
                if (c < NOUT) {
                    float v = acc[i][j] + bias[c];
                    if (RELU) v = fmaxf(v, 0.f);
                    out[(size_t)row * NOUT + c] = v;
                }
            }
        }
    }
}

// ---------------- launch ----------------

extern "C" void kernel_launch(void* const* d_in, const int* in_sizes, int n_in,
                              void* d_out, int out_size, void* d_ws, size_t ws_size,
                              hipStream_t stream) {
    const float* embed = (const float*)d_in[0];
    const float* Ws0   = (const float*)d_in[1];
    const float* Wn0   = (const float*)d_in[2];
    const float* b0    = (const float*)d_in[3];
    const float* Ws1   = (const float*)d_in[4];
    const float* Wn1   = (const float*)d_in[5];
    const float* b1    = (const float*)d_in[6];
    const float* Ws2   = (const float*)d_in[7];
    const float* Wn2   = (const float*)d_in[8];
    const float* b2    = (const float*)d_in[9];
    const int* input_nodes = (const int*)d_in[10];
    const int* src     = (const int*)d_in[11];
    const int* dst     = (const int*)d_in[12];
    float* out = (float*)d_out;

    // workspace carve-up (256B aligned)
    char* ws = (char*)d_ws;
    size_t off = 0;
    auto alloc = [&](size_t bytes) -> void* {
        void* p = ws + off;
        off += (bytes + 255) & ~(size_t)255;
        return p;
    };
    int*   cnt     = (int*)  alloc(sizeof(int)   * N_NODES);
    int*   fill    = (int*)  alloc(sizeof(int)   * N_NODES);
    int*   row_ptr = (int*)  alloc(sizeof(int)   * (N_NODES + 1));
    float* rdeg    = (float*)alloc(sizeof(float) * N_NODES);
    int*   col     = (int*)  alloc(sizeof(int)   * N_EDGES);
    float* h_a     = (float*)alloc(sizeof(float) * (size_t)N_NODES * F);
    float* h_b     = (float*)alloc(sizeof(float) * (size_t)N_NODES * F);
    float* meanb   = (float*)alloc(sizeof(float) * (size_t)N_NODES * F);
    (void)ws_size; (void)n_in; (void)in_sizes; (void)out_size;

    hipMemsetAsync(cnt,  0, sizeof(int) * N_NODES, stream);
    hipMemsetAsync(fill, 0, sizeof(int) * N_NODES, stream);

    const int EB = (N_EDGES + 255) / 256;
    count_kernel<<<EB, 256, 0, stream>>>(dst, cnt);
    scan_kernel<<<1, 1024, 0, stream>>>(cnt, row_ptr, rdeg);
    fill_kernel<<<EB, 256, 0, stream>>>(src, dst, row_ptr, fill, col);

    gather_embed_kernel<<<(N_NODES * (F / 4) + 255) / 256, 256, 0, stream>>>(embed, input_nodes, h_a);

    const int AGG_B  = (N_NODES + 3) / 4;
    const int GEMM_B = (N_NODES + 63) / 64;

    // layer 0: h_a -> h_b
    aggregate_kernel<<<AGG_B, 256, 0, stream>>>(h_a, row_ptr, col, rdeg, meanb);
    gemm_kernel<F, F, true><<<GEMM_B, 256, 0, stream>>>(meanb, h_a, Wn0, Ws0, b0, h_b);
    // layer 1: h_b -> h_a
    aggregate_kernel<<<AGG_B, 256, 0, stream>>>(h_b, row_ptr, col, rdeg, meanb);
    gemm_kernel<F, F, true><<<GEMM_B, 256, 0, stream>>>(meanb, h_b, Wn1, Ws1, b1, h_a);
    // layer 2: h_a -> out (47 classes, no relu)
    aggregate_kernel<<<AGG_B, 256, 0, stream>>>(h_a, row_ptr, col, rdeg, meanb);
    gemm_kernel<N_CLASSES, 64, false><<<GEMM_B, 256, 0, stream>>>(meanb, h_a, Wn2, Ws2, b2, out);
}

// Round 2
// 1243.396 us; speedup vs baseline: 1.3155x; 1.3155x over previous
//
#include <hip/hip_runtime.h>

#define N_NODES   100000
#define N_EDGES   1600000
#define F         128
#define N_CLASSES 47

// ---------------- CSR build ----------------

__global__ void count_kernel(const int* __restrict__ dst, int* __restrict__ cnt) {
    int e = blockIdx.x * blockDim.x + threadIdx.x;
    if (e < N_EDGES) atomicAdd(&cnt[dst[e]], 1);
}

__global__ void scan_kernel(const int* __restrict__ cnt, int* __restrict__ row_ptr,
                            float* __restrict__ rdeg) {
    const int T = 1024;
    const int CHUNK = (N_NODES + T - 1) / T;  // 98
    __shared__ int sums[T];
    __shared__ int offs[T + 1];
    int t = threadIdx.x;
    int lo = t * CHUNK;
    int hi = min(lo + CHUNK, N_NODES);
    int s = 0;
    for (int i = lo; i < hi; ++i) s += cnt[i];
    sums[t] = s;
    __syncthreads();
    if (t == 0) {
        int acc = 0;
        for (int i = 0; i < T; ++i) { offs[i] = acc; acc += sums[i]; }
        offs[T] = acc;
    }
    __syncthreads();
    int acc = offs[t];
    for (int i = lo; i < hi; ++i) {
        row_ptr[i] = acc;
        int c = cnt[i];
        rdeg[i] = 1.0f / (float)max(c, 1);
        acc += c;
    }
    if (t == T - 1) row_ptr[N_NODES] = offs[T];
}

__global__ void fill_kernel(const int* __restrict__ src, const int* __restrict__ dst,
                            const int* __restrict__ row_ptr, int* __restrict__ fill,
                            int* __restrict__ col) {
    int e = blockIdx.x * blockDim.x + threadIdx.x;
    if (e < N_EDGES) {
        int d = dst[e];
        int p = row_ptr[d] + atomicAdd(&fill[d], 1);
        col[p] = src[e];
    }
}

// ---------------- embedding gather ----------------

__global__ void gather_embed_kernel(const float* __restrict__ embed,
                                    const int* __restrict__ idx,
                                    float* __restrict__ h) {
    int i = blockIdx.x * blockDim.x + threadIdx.x;   // one float4 per thread
    const int TOTAL = N_NODES * (F / 4);
    if (i < TOTAL) {
        int node = i / (F / 4);
        int c4 = i % (F / 4);
        const float4* s = (const float4*)(embed + (size_t)idx[node] * F);
        ((float4*)(h + (size_t)node * F))[c4] = s[c4];
    }
}

// ---------------- pull aggregation: mean over in-neighbors ----------------
// one wave (64 lanes) per node; lane handles 2 consecutive feats (float2)

__global__ void aggregate_kernel(const float* __restrict__ h,
                                 const int* __restrict__ row_ptr,
                                 const int* __restrict__ col,
                                 const float* __restrict__ rdeg,
                                 float* __restrict__ mean) {
    int wave = threadIdx.x >> 6;
    int lane = threadIdx.x & 63;
    int v = blockIdx.x * 4 + wave;
    if (v >= N_NODES) return;
    int beg = row_ptr[v], end = row_ptr[v + 1];
    float ax = 0.f, ay = 0.f;
    for (int p = beg; p < end; ++p) {
        int u = col[p];
        float2 x = *(const float2*)(h + (size_t)u * F + lane * 2);
        ax += x.x; ay += x.y;
    }
    float r = rdeg[v];
    float2 o; o.x = ax * r; o.y = ay * r;
    *(float2*)(mean + (size_t)v * F + lane * 2) = o;
}

// ---------------- fused GEMM: out = mean@Wn + h@Ws + b (+relu) ----------------
// Canonical LDS-tiled SGEMM. BM=64, BN (128 or 64), BK=32, 256 threads.
// Thread micro-tile: TM=4 x TN=BN/16. K = 256 (phase 0: mean@Wn, phase 1: h@Ws).
// LDS ~25KB/block (BN=128) -> ~6 blocks/CU; weight reads are LDS broadcasts.

template<int NOUT, int BN, bool RELU>
__global__ __launch_bounds__(256)
void gemm_kernel(const float* __restrict__ mean, const float* __restrict__ h,
                 const float* __restrict__ Wn, const float* __restrict__ Ws,
                 const float* __restrict__ bias, float* __restrict__ out) {
    constexpr int BM = 64;
    constexpr int BK = 32;
    constexpr int TM = 4;
    constexpr int TN = BN / 16;       // 8 (BN=128) or 4 (BN=64)
    constexpr int LDW = BN + 4;       // padded leading dim for W tile

    __shared__ float As[BK][BM];      // A^T tile: As[k][m]
    __shared__ float Bs[BK][LDW];     // W tile:   Bs[k][n]

    const int t    = threadIdx.x;
    const int row0 = blockIdx.x * BM;
    const int tr   = t >> 4;          // 0..15  (row group)
    const int tc   = t & 15;          // 0..15  (col group)

    float acc[TM][TN];
    #pragma unroll
    for (int m = 0; m < TM; ++m)
        #pragma unroll
        for (int n = 0; n < TN; ++n) acc[m][n] = 0.f;

    // 8 k-tiles: kt 0..3 -> (mean, Wn), kt 4..7 -> (h, Ws)
    #pragma unroll 1
    for (int kt = 0; kt < 8; ++kt) {
        const float* __restrict__ A = (kt < 4) ? mean : h;
        const float* __restrict__ W = (kt < 4) ? Wn   : Ws;
        const int k0 = (kt & 3) * BK;

        // ---- stage A tile (BM x BK) transposed into As[k][m] ----
        #pragma unroll
        for (int i = 0; i < 2; ++i) {
            int id   = t + i * 256;          // 0..511
            int arow = id >> 3;              // 0..63
            int ak4  = id & 7;               // float4 index in k-tile
            float4 a4 = make_float4(0.f, 0.f, 0.f, 0.f);
            int row = row0 + arow;
            if (row < N_NODES)
                a4 = *(const float4*)(A + (size_t)row * F + k0 + ak4 * 4);
            As[ak4 * 4 + 0][arow] = a4.x;
            As[ak4 * 4 + 1][arow] = a4.y;
            As[ak4 * 4 + 2][arow] = a4.z;
            As[ak4 * 4 + 3][arow] = a4.w;
        }

        // ---- stage W tile (BK x BN) into Bs[k][n] ----
        if (NOUT == BN) {
            // dense 128-wide: vectorized
            #pragma unroll
            for (int i = 0; i < (BK * BN) / (256 * 4); ++i) {
                int id  = t + i * 256;
                int wk  = id >> 5;           // 0..31
                int wn4 = id & 31;           // float4 col group
                float4 w4 = *(const float4*)(W + (size_t)(k0 + wk) * NOUT + wn4 * 4);
                *(float4*)(&Bs[wk][wn4 * 4]) = w4;
            }
        } else {
            // NOUT=47 padded to BN=64: guarded scalar
            int wk = t >> 3;                 // 0..31
            int c0 = (t & 7) * 8;            // 0,8,...,56
            #pragma unroll
            for (int j = 0; j < 8; ++j) {
                int c = c0 + j;
                Bs[wk][c] = (c < NOUT) ? W[(size_t)(k0 + wk) * NOUT + c] : 0.f;
            }
        }
        __syncthreads();

        // ---- compute ----
        #pragma unroll 8
        for (int k = 0; k < BK; ++k) {
            float4 a = *(const float4*)(&As[k][tr * TM]);
            float w[TN];
            #pragma unroll
            for (int n4 = 0; n4 < TN / 4; ++n4)
                *(float4*)(&w[n4 * 4]) = *(const float4*)(&Bs[k][tc * TN + n4 * 4]);
            float av[TM] = {a.x, a.y, a.z, a.w};
            #pragma unroll
            for (int m = 0; m < TM; ++m)
                #pragma unroll
                for (int n = 0; n < TN; ++n)
                    acc[m][n] = fmaf(av[m], w[n], acc[m][n]);
        }
        __syncthreads();
    }

    // ---- epilogue: bias (+relu), store ----
    #pragma unroll
    for (int m = 0; m < TM; ++m) {
        int row = row0 + tr * TM + m;
        if (row >= N_NODES) continue;
        if (NOUT == BN) {
            #pragma unroll
            for (int n4 = 0; n4 < TN / 4; ++n4) {
                int c = tc * TN + n4 * 4;
                float4 v;
                v.x = acc[m][n4 * 4 + 0] + bias[c + 0];
                v.y = acc[m][n4 * 4 + 1] + bias[c + 1];
                v.z = acc[m][n4 * 4 + 2] + bias[c + 2];
                v.w = acc[m][n4 * 4 + 3] + bias[c + 3];
                if (RELU) {
                    v.x = fmaxf(v.x, 0.f); v.y = fmaxf(v.y, 0.f);
                    v.z = fmaxf(v.z, 0.f); v.w = fmaxf(v.w, 0.f);
                }
                *(float4*)(out + (size_t)row * NOUT + c) = v;
            }
        } else {
            #pragma unroll
            for (int n = 0; n < TN; ++n) {
                int c = tc * TN + n;
                if (c < NOUT) {
                    float v = acc[m][n] + bias[c];
                    if (RELU) v = fmaxf(v, 0.f);
                    out[(size_t)row * NOUT + c] = v;
                }
            }
        }
    }
}

// ---------------- launch ----------------

extern "C" void kernel_launch(void* const* d_in, const int* in_sizes, int n_in,
                              void* d_out, int out_size, void* d_ws, size_t ws_size,
                              hipStream_t stream) {
    const float* embed = (const float*)d_in[0];
    const float* Ws0   = (const float*)d_in[1];
    const float* Wn0   = (const float*)d_in[2];
    const float* b0    = (const float*)d_in[3];
    const float* Ws1   = (const float*)d_in[4];
    const float* Wn1   = (const float*)d_in[5];
    const float* b1    = (const float*)d_in[6];
    const float* Ws2   = (const float*)d_in[7];
    const float* Wn2   = (const float*)d_in[8];
    const float* b2    = (const float*)d_in[9];
    const int* input_nodes = (const int*)d_in[10];
    const int* src     = (const int*)d_in[11];
    const int* dst     = (const int*)d_in[12];
    float* out = (float*)d_out;

    // workspace carve-up (256B aligned)
    char* ws = (char*)d_ws;
    size_t off = 0;
    auto alloc = [&](size_t bytes) -> void* {
        void* p = ws + off;
        off += (bytes + 255) & ~(size_t)255;
        return p;
    };
    int*   cnt     = (int*)  alloc(sizeof(int)   * N_NODES);
    int*   fill    = (int*)  alloc(sizeof(int)   * N_NODES);
    int*   row_ptr = (int*)  alloc(sizeof(int)   * (N_NODES + 1));
    float* rdeg    = (float*)alloc(sizeof(float) * N_NODES);
    int*   col     = (int*)  alloc(sizeof(int)   * N_EDGES);
    float* h_a     = (float*)alloc(sizeof(float) * (size_t)N_NODES * F);
    float* h_b     = (float*)alloc(sizeof(float) * (size_t)N_NODES * F);
    float* meanb   = (float*)alloc(sizeof(float) * (size_t)N_NODES * F);
    (void)ws_size; (void)n_in; (void)in_sizes; (void)out_size;

    hipMemsetAsync(cnt,  0, sizeof(int) * N_NODES, stream);
    hipMemsetAsync(fill, 0, sizeof(int) * N_NODES, stream);

    const int EB = (N_EDGES + 255) / 256;
    count_kernel<<<EB, 256, 0, stream>>>(dst, cnt);
    scan_kernel<<<1, 1024, 0, stream>>>(cnt, row_ptr, rdeg);
    fill_kernel<<<EB, 256, 0, stream>>>(src, dst, row_ptr, fill, col);

    gather_embed_kernel<<<(N_NODES * (F / 4) + 255) / 256, 256, 0, stream>>>(embed, input_nodes, h_a);

    const int AGG_B  = (N_NODES + 3) / 4;
    const int GEMM_B = (N_NODES + 63) / 64;

    // layer 0: h_a -> h_b
    aggregate_kernel<<<AGG_B, 256, 0, stream>>>(h_a, row_ptr, col, rdeg, meanb);
    gemm_kernel<F, F, true><<<GEMM_B, 256, 0, stream>>>(meanb, h_a, Wn0, Ws0, b0, h_b);
    // layer 1: h_b -> h_a
    aggregate_kernel<<<AGG_B, 256, 0, stream>>>(h_b, row_ptr, col, rdeg, meanb);
    gemm_kernel<F, F, true><<<GEMM_B, 256, 0, stream>>>(meanb, h_b, Wn1, Ws1, b1, h_a);
    // layer 2: h_a -> out (47 classes, no relu)
    aggregate_kernel<<<AGG_B, 256, 0, stream>>>(h_a, row_ptr, col, rdeg, meanb);
    gemm_kernel<N_CLASSES, 64, false><<<GEMM_B, 256, 0, stream>>>(meanb, h_a, Wn2, Ws2, b2, out);
}

// Round 3
// 1024.360 us; speedup vs baseline: 1.5967x; 1.2138x over previous
//
#include <hip/hip_runtime.h>

#define N_NODES   100000
#define N_EDGES   1600000
#define F         128
#define N_CLASSES 47
#define SCAN_B    98   // ceil(N_NODES / 1024)

// ---------------- CSR build ----------------

__global__ void count_kernel(const int* __restrict__ dst, int* __restrict__ cnt) {
    int e = blockIdx.x * blockDim.x + threadIdx.x;
    if (e < N_EDGES) atomicAdd(&cnt[dst[e]], 1);
}

// phase 1: per-block sums of cnt (coalesced + LDS tree reduce)
__global__ void scan1_kernel(const int* __restrict__ cnt, int* __restrict__ blk_sums) {
    __shared__ int red[1024];
    int t = threadIdx.x;
    int i = blockIdx.x * 1024 + t;
    red[t] = (i < N_NODES) ? cnt[i] : 0;
    __syncthreads();
    #pragma unroll
    for (int off = 512; off > 0; off >>= 1) {
        if (t < off) red[t] += red[t + off];
        __syncthreads();
    }
    if (t == 0) blk_sums[blockIdx.x] = red[0];
}

// phase 2: exclusive scan of the 98 block sums (single tiny block)
__global__ void scan2_kernel(int* __restrict__ blk_sums, int* __restrict__ row_ptr) {
    __shared__ int s[128];
    int t = threadIdx.x;
    int v = (t < SCAN_B) ? blk_sums[t] : 0;
    s[t] = v;
    __syncthreads();
    #pragma unroll
    for (int off = 1; off < 128; off <<= 1) {
        int add = (t >= off) ? s[t - off] : 0;
        __syncthreads();
        s[t] += add;
        __syncthreads();
    }
    if (t < SCAN_B) blk_sums[t] = s[t] - v;     // exclusive offset
    if (t == SCAN_B - 1) row_ptr[N_NODES] = s[t];
}

// phase 3: block-local inclusive scan + block offset -> row_ptr; also rdeg
__global__ void scan3_kernel(const int* __restrict__ cnt, const int* __restrict__ blk_offs,
                             int* __restrict__ row_ptr, float* __restrict__ rdeg) {
    __shared__ int s[1024];
    int t = threadIdx.x;
    int i = blockIdx.x * 1024 + t;
    int c = (i < N_NODES) ? cnt[i] : 0;
    s[t] = c;
    __syncthreads();
    #pragma unroll
    for (int off = 1; off < 1024; off <<= 1) {
        int add = (t >= off) ? s[t - off] : 0;
        __syncthreads();
        s[t] += add;
        __syncthreads();
    }
    if (i < N_NODES) {
        row_ptr[i] = s[t] - c + blk_offs[blockIdx.x];
        rdeg[i] = 1.0f / (float)max(c, 1);
    }
}

__global__ void fill_kernel(const int* __restrict__ src, const int* __restrict__ dst,
                            const int* __restrict__ row_ptr, int* __restrict__ fill,
                            int* __restrict__ col) {
    int e = blockIdx.x * blockDim.x + threadIdx.x;
    if (e < N_EDGES) {
        int d = dst[e];
        int p = row_ptr[d] + atomicAdd(&fill[d], 1);
        col[p] = src[e];
    }
}

// ---------------- embedding gather ----------------

__global__ void gather_embed_kernel(const float* __restrict__ embed,
                                    const int* __restrict__ idx,
                                    float* __restrict__ h) {
    int i = blockIdx.x * blockDim.x + threadIdx.x;   // one float4 per thread
    const int TOTAL = N_NODES * (F / 4);
    if (i < TOTAL) {
        int node = i / (F / 4);
        int c4 = i % (F / 4);
        const float4* s = (const float4*)(embed + (size_t)idx[node] * F);
        ((float4*)(h + (size_t)node * F))[c4] = s[c4];
    }
}

// ---------------- pull aggregation: mean over in-neighbors ----------------
// one wave (64 lanes) per node; lane handles 2 consecutive feats (float2)

__global__ void aggregate_kernel(const float* __restrict__ h,
                                 const int* __restrict__ row_ptr,
                                 const int* __restrict__ col,
                                 const float* __restrict__ rdeg,
                                 float* __restrict__ mean) {
    int wave = threadIdx.x >> 6;
    int lane = threadIdx.x & 63;
    int v = blockIdx.x * 4 + wave;
    if (v >= N_NODES) return;
    int beg = row_ptr[v], end = row_ptr[v + 1];
    float ax = 0.f, ay = 0.f;
    for (int p = beg; p < end; ++p) {
        int u = col[p];
        float2 x = *(const float2*)(h + (size_t)u * F + lane * 2);
        ax += x.x; ay += x.y;
    }
    float r = rdeg[v];
    float2 o; o.x = ax * r; o.y = ay * r;
    *(float2*)(mean + (size_t)v * F + lane * 2) = o;
}

// ---------------- fused GEMM: out = mean@Wn + h@Ws + b (+relu) ----------------
// Canonical LDS-tiled SGEMM. BM=64, BN (128 or 64), BK=32, 256 threads.
// Thread micro-tile: TM=4 x TN=BN/16. K = 256 (phase 0: mean@Wn, phase 1: h@Ws).

template<int NOUT, int BN, bool RELU>
__global__ __launch_bounds__(256)
void gemm_kernel(const float* __restrict__ mean, const float* __restrict__ h,
                 const float* __restrict__ Wn, const float* __restrict__ Ws,
                 const float* __restrict__ bias, float* __restrict__ out) {
    constexpr int BM = 64;
    constexpr int BK = 32;
    constexpr int TM = 4;
    constexpr int TN = BN / 16;       // 8 (BN=128) or 4 (BN=64)
    constexpr int LDW = BN + 4;       // padded leading dim for W tile

    __shared__ float As[BK][BM];      // A^T tile: As[k][m]
    __shared__ float Bs[BK][LDW];     // W tile:   Bs[k][n]

    const int t    = threadIdx.x;
    const int row0 = blockIdx.x * BM;
    const int tr   = t >> 4;          // 0..15  (row group)
    const int tc   = t & 15;          // 0..15  (col group)

    float acc[TM][TN];
    #pragma unroll
    for (int m = 0; m < TM; ++m)
        #pragma unroll
        for (int n = 0; n < TN; ++n) acc[m][n] = 0.f;

    // 8 k-tiles: kt 0..3 -> (mean, Wn), kt 4..7 -> (h, Ws)
    #pragma unroll 1
    for (int kt = 0; kt < 8; ++kt) {
        const float* __restrict__ A = (kt < 4) ? mean : h;
        const float* __restrict__ W = (kt < 4) ? Wn   : Ws;
        const int k0 = (kt & 3) * BK;

        // ---- stage A tile (BM x BK) transposed into As[k][m] ----
        #pragma unroll
        for (int i = 0; i < 2; ++i) {
            int id   = t + i * 256;          // 0..511
            int arow = id >> 3;              // 0..63
            int ak4  = id & 7;               // float4 index in k-tile
            float4 a4 = make_float4(0.f, 0.f, 0.f, 0.f);
            int row = row0 + arow;
            if (row < N_NODES)
                a4 = *(const float4*)(A + (size_t)row * F + k0 + ak4 * 4);
            As[ak4 * 4 + 0][arow] = a4.x;
            As[ak4 * 4 + 1][arow] = a4.y;
            As[ak4 * 4 + 2][arow] = a4.z;
            As[ak4 * 4 + 3][arow] = a4.w;
        }

        // ---- stage W tile (BK x BN) into Bs[k][n] ----
        if (NOUT == BN) {
            #pragma unroll
            for (int i = 0; i < (BK * BN) / (256 * 4); ++i) {
                int id  = t + i * 256;
                int wk  = id >> 5;           // 0..31
                int wn4 = id & 31;           // float4 col group
                float4 w4 = *(const float4*)(W + (size_t)(k0 + wk) * NOUT + wn4 * 4);
                *(float4*)(&Bs[wk][wn4 * 4]) = w4;
            }
        } else {
            int wk = t >> 3;                 // 0..31
            int c0 = (t & 7) * 8;            // 0,8,...,56
            #pragma unroll
            for (int j = 0; j < 8; ++j) {
                int c = c0 + j;
                Bs[wk][c] = (c < NOUT) ? W[(size_t)(k0 + wk) * NOUT + c] : 0.f;
            }
        }
        __syncthreads();

        // ---- compute ----
        #pragma unroll 8
        for (int k = 0; k < BK; ++k) {
            float4 a = *(const float4*)(&As[k][tr * TM]);
            float w[TN];
            #pragma unroll
            for (int n4 = 0; n4 < TN / 4; ++n4)
                *(float4*)(&w[n4 * 4]) = *(const float4*)(&Bs[k][tc * TN + n4 * 4]);
            float av[TM] = {a.x, a.y, a.z, a.w};
            #pragma unroll
            for (int m = 0; m < TM; ++m)
                #pragma unroll
                for (int n = 0; n < TN; ++n)
                    acc[m][n] = fmaf(av[m], w[n], acc[m][n]);
        }
        __syncthreads();
    }

    // ---- epilogue: bias (+relu), store ----
    #pragma unroll
    for (int m = 0; m < TM; ++m) {
        int row = row0 + tr * TM + m;
        if (row >= N_NODES) continue;
        if (NOUT == BN) {
            #pragma unroll
            for (int n4 = 0; n4 < TN / 4; ++n4) {
                int c = tc * TN + n4 * 4;
                float4 v;
                v.x = acc[m][n4 * 4 + 0] + bias[c + 0];
                v.y = acc[m][n4 * 4 + 1] + bias[c + 1];
                v.z = acc[m][n4 * 4 + 2] + bias[c + 2];
                v.w = acc[m][n4 * 4 + 3] + bias[c + 3];
                if (RELU) {
                    v.x = fmaxf(v.x, 0.f); v.y = fmaxf(v.y, 0.f);
                    v.z = fmaxf(v.z, 0.f); v.w = fmaxf(v.w, 0.f);
                }
                *(float4*)(out + (size_t)row * NOUT + c) = v;
            }
        } else {
            #pragma unroll
            for (int n = 0; n < TN; ++n) {
                int c = tc * TN + n;
                if (c < NOUT) {
                    float v = acc[m][n] + bias[c];
                    if (RELU) v = fmaxf(v, 0.f);
                    out[(size_t)row * NOUT + c] = v;
                }
            }
        }
    }
}

// ---------------- launch ----------------

extern "C" void kernel_launch(void* const* d_in, const int* in_sizes, int n_in,
                              void* d_out, int out_size, void* d_ws, size_t ws_size,
                              hipStream_t stream) {
    const float* embed = (const float*)d_in[0];
    const float* Ws0   = (const float*)d_in[1];
    const float* Wn0   = (const float*)d_in[2];
    const float* b0    = (const float*)d_in[3];
    const float* Ws1   = (const float*)d_in[4];
    const float* Wn1   = (const float*)d_in[5];
    const float* b1    = (const float*)d_in[6];
    const float* Ws2   = (const float*)d_in[7];
    const float* Wn2   = (const float*)d_in[8];
    const float* b2    = (const float*)d_in[9];
    const int* input_nodes = (const int*)d_in[10];
    const int* src     = (const int*)d_in[11];
    const int* dst     = (const int*)d_in[12];
    float* out = (float*)d_out;

    // workspace carve-up (256B aligned)
    char* ws = (char*)d_ws;
    size_t off = 0;
    auto alloc = [&](size_t bytes) -> void* {
        void* p = ws + off;
        off += (bytes + 255) & ~(size_t)255;
        return p;
    };
    int*   cnt      = (int*)  alloc(sizeof(int)   * N_NODES);
    int*   fill     = (int*)  alloc(sizeof(int)   * N_NODES);
    int*   row_ptr  = (int*)  alloc(sizeof(int)   * (N_NODES + 1));
    float* rdeg     = (float*)alloc(sizeof(float) * N_NODES);
    int*   col      = (int*)  alloc(sizeof(int)   * N_EDGES);
    int*   blk_sums = (int*)  alloc(sizeof(int)   * 128);
    float* h_a      = (float*)alloc(sizeof(float) * (size_t)N_NODES * F);
    float* h_b      = (float*)alloc(sizeof(float) * (size_t)N_NODES * F);
    float* meanb    = (float*)alloc(sizeof(float) * (size_t)N_NODES * F);
    (void)ws_size; (void)n_in; (void)in_sizes; (void)out_size;

    hipMemsetAsync(cnt,  0, sizeof(int) * N_NODES, stream);
    hipMemsetAsync(fill, 0, sizeof(int) * N_NODES, stream);

    const int EB = (N_EDGES + 255) / 256;
    count_kernel<<<EB, 256, 0, stream>>>(dst, cnt);
    scan1_kernel<<<SCAN_B, 1024, 0, stream>>>(cnt, blk_sums);
    scan2_kernel<<<1, 128, 0, stream>>>(blk_sums, row_ptr);
    scan3_kernel<<<SCAN_B, 1024, 0, stream>>>(cnt, blk_sums, row_ptr, rdeg);
    fill_kernel<<<EB, 256, 0, stream>>>(src, dst, row_ptr, fill, col);

    gather_embed_kernel<<<(N_NODES * (F / 4) + 255) / 256, 256, 0, stream>>>(embed, input_nodes, h_a);

    const int AGG_B  = (N_NODES + 3) / 4;
    const int GEMM_B = (N_NODES + 63) / 64;

    // layer 0: h_a -> h_b
    aggregate_kernel<<<AGG_B, 256, 0, stream>>>(h_a, row_ptr, col, rdeg, meanb);
    gemm_kernel<F, F, true><<<GEMM_B, 256, 0, stream>>>(meanb, h_a, Wn0, Ws0, b0, h_b);
    // layer 1: h_b -> h_a
    aggregate_kernel<<<AGG_B, 256, 0, stream>>>(h_b, row_ptr, col, rdeg, meanb);
    gemm_kernel<F, F, true><<<GEMM_B, 256, 0, stream>>>(meanb, h_b, Wn1, Ws1, b1, h_a);
    // layer 2: h_a -> out (47 classes, no relu)
    aggregate_kernel<<<AGG_B, 256, 0, stream>>>(h_a, row_ptr, col, rdeg, meanb);
    gemm_kernel<N_CLASSES, 64, false><<<GEMM_B, 256, 0, stream>>>(meanb, h_a, Wn2, Ws2, b2, out);
}

// Round 4
// 763.473 us; speedup vs baseline: 2.1424x; 1.3417x over previous
//
#include <hip/hip_runtime.h>

#define N_NODES   100000
#define N_EDGES   1600000
#define F         128
#define N_CLASSES 47
#define SCAN_B    98   // ceil(N_NODES / 1024)

typedef unsigned int  uint32;
typedef unsigned short ushort16;

// bf16 helpers (RNE)
__device__ __forceinline__ uint32 f2bf(float f) {
    uint32 u = __float_as_uint(f);
    return (u + 0x7FFFu + ((u >> 16) & 1u)) >> 16;
}
__device__ __forceinline__ float bfl(uint32 u) {  // low bf16 -> f32
    return __uint_as_float(u << 16);
}
__device__ __forceinline__ float bfh(uint32 u) {  // high bf16 -> f32
    return __uint_as_float(u & 0xFFFF0000u);
}

// ---------------- CSR build ----------------

__global__ void count_kernel(const int* __restrict__ dst, int* __restrict__ cnt) {
    int e = blockIdx.x * blockDim.x + threadIdx.x;
    if (e < N_EDGES) atomicAdd(&cnt[dst[e]], 1);
}

__global__ void scan1_kernel(const int* __restrict__ cnt, int* __restrict__ blk_sums) {
    __shared__ int red[1024];
    int t = threadIdx.x;
    int i = blockIdx.x * 1024 + t;
    red[t] = (i < N_NODES) ? cnt[i] : 0;
    __syncthreads();
    #pragma unroll
    for (int off = 512; off > 0; off >>= 1) {
        if (t < off) red[t] += red[t + off];
        __syncthreads();
    }
    if (t == 0) blk_sums[blockIdx.x] = red[0];
}

__global__ void scan2_kernel(int* __restrict__ blk_sums, int* __restrict__ row_ptr) {
    __shared__ int s[128];
    int t = threadIdx.x;
    int v = (t < SCAN_B) ? blk_sums[t] : 0;
    s[t] = v;
    __syncthreads();
    #pragma unroll
    for (int off = 1; off < 128; off <<= 1) {
        int add = (t >= off) ? s[t - off] : 0;
        __syncthreads();
        s[t] += add;
        __syncthreads();
    }
    if (t < SCAN_B) blk_sums[t] = s[t] - v;     // exclusive offset
    if (t == SCAN_B - 1) row_ptr[N_NODES] = s[t];
}

__global__ void scan3_kernel(const int* __restrict__ cnt, const int* __restrict__ blk_offs,
                             int* __restrict__ row_ptr, float* __restrict__ rdeg) {
    __shared__ int s[1024];
    int t = threadIdx.x;
    int i = blockIdx.x * 1024 + t;
    int c = (i < N_NODES) ? cnt[i] : 0;
    s[t] = c;
    __syncthreads();
    #pragma unroll
    for (int off = 1; off < 1024; off <<= 1) {
        int add = (t >= off) ? s[t - off] : 0;
        __syncthreads();
        s[t] += add;
        __syncthreads();
    }
    if (i < N_NODES) {
        row_ptr[i] = s[t] - c + blk_offs[blockIdx.x];
        rdeg[i] = 1.0f / (float)max(c, 1);
    }
}

__global__ void fill_kernel(const int* __restrict__ src, const int* __restrict__ dst,
                            const int* __restrict__ row_ptr, int* __restrict__ fill,
                            int* __restrict__ col) {
    int e = blockIdx.x * blockDim.x + threadIdx.x;
    if (e < N_EDGES) {
        int d = dst[e];
        int p = row_ptr[d] + atomicAdd(&fill[d], 1);
        col[p] = src[e];
    }
}

// ---------------- embedding gather: fp32 embed -> bf16 h ----------------

__global__ void gather_embed_kernel(const float* __restrict__ embed,
                                    const int* __restrict__ idx,
                                    ushort16* __restrict__ h) {
    int i = blockIdx.x * blockDim.x + threadIdx.x;   // one 4-feat group per thread
    const int TOTAL = N_NODES * (F / 4);
    if (i < TOTAL) {
        int node = i >> 5;
        int c4 = i & 31;
        float4 v = ((const float4*)(embed + (size_t)idx[node] * F))[c4];
        uint2 o;
        o.x = f2bf(v.x) | (f2bf(v.y) << 16);
        o.y = f2bf(v.z) | (f2bf(v.w) << 16);
        ((uint2*)(h + (size_t)node * F))[c4] = o;
    }
}

// ---------------- pull aggregation (bf16 h -> fp32 mean) ----------------
// one wave per node; lane handles 2 feats (one packed uint32 = 2 bf16).
// 4-way unrolled: 4 independent gathers in flight per wave.

__global__ void aggregate_kernel(const ushort16* __restrict__ h,
                                 const int* __restrict__ row_ptr,
                                 const int* __restrict__ col,
                                 const float* __restrict__ rdeg,
                                 float* __restrict__ mean) {
    int wave = threadIdx.x >> 6;
    int lane = threadIdx.x & 63;
    int v = blockIdx.x * 4 + wave;
    if (v >= N_NODES) return;
    const uint32* hp = (const uint32*)h;   // 64 uints per row
    int beg = row_ptr[v], end = row_ptr[v + 1];
    float ax = 0.f, ay = 0.f;
    int p = beg;
    for (; p + 4 <= end; p += 4) {
        int u0 = col[p], u1 = col[p + 1], u2 = col[p + 2], u3 = col[p + 3];
        uint32 x0 = hp[(size_t)u0 * 64 + lane];
        uint32 x1 = hp[(size_t)u1 * 64 + lane];
        uint32 x2 = hp[(size_t)u2 * 64 + lane];
        uint32 x3 = hp[(size_t)u3 * 64 + lane];
        ax += bfl(x0) + bfl(x1) + bfl(x2) + bfl(x3);
        ay += bfh(x0) + bfh(x1) + bfh(x2) + bfh(x3);
    }
    for (; p < end; ++p) {
        uint32 x = hp[(size_t)col[p] * 64 + lane];
        ax += bfl(x);
        ay += bfh(x);
    }
    float r = rdeg[v];
    float2 o; o.x = ax * r; o.y = ay * r;
    *(float2*)(mean + (size_t)v * F + lane * 2) = o;
}

// ---------------- fused GEMM: out = mean@Wn + h@Ws + b (+relu) ----------------
// mean fp32, h bf16 (converted during LDS staging), weights fp32, acc fp32.
// OUTBF: write bf16 (hidden layers) vs fp32 (final).

template<int NOUT, int BN, bool RELU, bool OUTBF>
__global__ __launch_bounds__(256)
void gemm_kernel(const float* __restrict__ mean, const ushort16* __restrict__ h,
                 const float* __restrict__ Wn, const float* __restrict__ Ws,
                 const float* __restrict__ bias, void* __restrict__ out_) {
    constexpr int BM = 64;
    constexpr int BK = 32;
    constexpr int TM = 4;
    constexpr int TN = BN / 16;       // 8 (BN=128) or 4 (BN=64)
    constexpr int LDW = BN + 4;

    __shared__ float As[BK][BM];      // A^T tile
    __shared__ float Bs[BK][LDW];     // W tile

    const int t    = threadIdx.x;
    const int row0 = blockIdx.x * BM;
    const int tr   = t >> 4;
    const int tc   = t & 15;

    float acc[TM][TN];
    #pragma unroll
    for (int m = 0; m < TM; ++m)
        #pragma unroll
        for (int n = 0; n < TN; ++n) acc[m][n] = 0.f;

    #pragma unroll 1
    for (int kt = 0; kt < 8; ++kt) {
        const float* __restrict__ W = (kt < 4) ? Wn : Ws;
        const int k0 = (kt & 3) * BK;

        // ---- stage A tile (BM x BK) transposed into As[k][m] ----
        #pragma unroll
        for (int i = 0; i < 2; ++i) {
            int id   = t + i * 256;          // 0..511
            int arow = id >> 3;              // 0..63
            int ak4  = id & 7;               // 4-feat group in k-tile
            float4 a4 = make_float4(0.f, 0.f, 0.f, 0.f);
            int row = row0 + arow;
            if (row < N_NODES) {
                if (kt < 4) {
                    a4 = *(const float4*)(mean + (size_t)row * F + k0 + ak4 * 4);
                } else {
                    uint2 u = *(const uint2*)((const ushort16*)h + (size_t)row * F + k0 + ak4 * 4);
                    a4.x = bfl(u.x); a4.y = bfh(u.x);
                    a4.z = bfl(u.y); a4.w = bfh(u.y);
                }
            }
            As[ak4 * 4 + 0][arow] = a4.x;
            As[ak4 * 4 + 1][arow] = a4.y;
            As[ak4 * 4 + 2][arow] = a4.z;
            As[ak4 * 4 + 3][arow] = a4.w;
        }

        // ---- stage W tile (BK x BN) into Bs[k][n] ----
        if (NOUT == BN) {
            #pragma unroll
            for (int i = 0; i < (BK * BN) / (256 * 4); ++i) {
                int id  = t + i * 256;
                int wk  = id >> 5;
                int wn4 = id & 31;
                float4 w4 = *(const float4*)(W + (size_t)(k0 + wk) * NOUT + wn4 * 4);
                *(float4*)(&Bs[wk][wn4 * 4]) = w4;
            }
        } else {
            int wk = t >> 3;
            int c0 = (t & 7) * 8;
            #pragma unroll
            for (int j = 0; j < 8; ++j) {
                int c = c0 + j;
                Bs[wk][c] = (c < NOUT) ? W[(size_t)(k0 + wk) * NOUT + c] : 0.f;
            }
        }
        __syncthreads();

        // ---- compute ----
        #pragma unroll 8
        for (int k = 0; k < BK; ++k) {
            float4 a = *(const float4*)(&As[k][tr * TM]);
            float w[TN];
            #pragma unroll
            for (int n4 = 0; n4 < TN / 4; ++n4)
                *(float4*)(&w[n4 * 4]) = *(const float4*)(&Bs[k][tc * TN + n4 * 4]);
            float av[TM] = {a.x, a.y, a.z, a.w};
            #pragma unroll
            for (int m = 0; m < TM; ++m)
                #pragma unroll
                for (int n = 0; n < TN; ++n)
                    acc[m][n] = fmaf(av[m], w[n], acc[m][n]);
        }
        __syncthreads();
    }

    // ---- epilogue ----
    #pragma unroll
    for (int m = 0; m < TM; ++m) {
        int row = row0 + tr * TM + m;
        if (row >= N_NODES) continue;
        if (NOUT == BN) {
            #pragma unroll
            for (int n4 = 0; n4 < TN / 4; ++n4) {
                int c = tc * TN + n4 * 4;
                float4 v;
                v.x = acc[m][n4 * 4 + 0] + bias[c + 0];
                v.y = acc[m][n4 * 4 + 1] + bias[c + 1];
                v.z = acc[m][n4 * 4 + 2] + bias[c + 2];
                v.w = acc[m][n4 * 4 + 3] + bias[c + 3];
                if (RELU) {
                    v.x = fmaxf(v.x, 0.f); v.y = fmaxf(v.y, 0.f);
                    v.z = fmaxf(v.z, 0.f); v.w = fmaxf(v.w, 0.f);
                }
                if (OUTBF) {
                    uint2 o;
                    o.x = f2bf(v.x) | (f2bf(v.y) << 16);
                    o.y = f2bf(v.z) | (f2bf(v.w) << 16);
                    *(uint2*)((ushort16*)out_ + (size_t)row * NOUT + c) = o;
                } else {
                    *(float4*)((float*)out_ + (size_t)row * NOUT + c) = v;
                }
            }
        } else {
            #pragma unroll
            for (int n = 0; n < TN; ++n) {
                int c = tc * TN + n;
                if (c < NOUT) {
                    float v = acc[m][n] + bias[c];
                    if (RELU) v = fmaxf(v, 0.f);
                    ((float*)out_)[(size_t)row * NOUT + c] = v;
                }
            }
        }
    }
}

// ---------------- launch ----------------

extern "C" void kernel_launch(void* const* d_in, const int* in_sizes, int n_in,
                              void* d_out, int out_size, void* d_ws, size_t ws_size,
                              hipStream_t stream) {
    const float* embed = (const float*)d_in[0];
    const float* Ws0   = (const float*)d_in[1];
    const float* Wn0   = (const float*)d_in[2];
    const float* b0    = (const float*)d_in[3];
    const float* Ws1   = (const float*)d_in[4];
    const float* Wn1   = (const float*)d_in[5];
    const float* b1    = (const float*)d_in[6];
    const float* Ws2   = (const float*)d_in[7];
    const float* Wn2   = (const float*)d_in[8];
    const float* b2    = (const float*)d_in[9];
    const int* input_nodes = (const int*)d_in[10];
    const int* src     = (const int*)d_in[11];
    const int* dst     = (const int*)d_in[12];
    float* out = (float*)d_out;

    char* ws = (char*)d_ws;
    size_t off = 0;
    auto alloc = [&](size_t bytes) -> void* {
        void* p = ws + off;
        off += (bytes + 255) & ~(size_t)255;
        return p;
    };
    int*      cnt      = (int*)     alloc(sizeof(int)   * N_NODES);
    int*      fill     = (int*)     alloc(sizeof(int)   * N_NODES);
    int*      row_ptr  = (int*)     alloc(sizeof(int)   * (N_NODES + 1));
    float*    rdeg     = (float*)   alloc(sizeof(float) * N_NODES);
    int*      col      = (int*)     alloc(sizeof(int)   * N_EDGES);
    int*      blk_sums = (int*)     alloc(sizeof(int)   * 128);
    ushort16* h_a      = (ushort16*)alloc(sizeof(ushort16) * (size_t)N_NODES * F);
    ushort16* h_b      = (ushort16*)alloc(sizeof(ushort16) * (size_t)N_NODES * F);
    float*    meanb    = (float*)   alloc(sizeof(float) * (size_t)N_NODES * F);
    (void)ws_size; (void)n_in; (void)in_sizes; (void)out_size;

    hipMemsetAsync(cnt,  0, sizeof(int) * N_NODES, stream);
    hipMemsetAsync(fill, 0, sizeof(int) * N_NODES, stream);

    const int EB = (N_EDGES + 255) / 256;
    count_kernel<<<EB, 256, 0, stream>>>(dst, cnt);
    scan1_kernel<<<SCAN_B, 1024, 0, stream>>>(cnt, blk_sums);
    scan2_kernel<<<1, 128, 0, stream>>>(blk_sums, row_ptr);
    scan3_kernel<<<SCAN_B, 1024, 0, stream>>>(cnt, blk_sums, row_ptr, rdeg);
    fill_kernel<<<EB, 256, 0, stream>>>(src, dst, row_ptr, fill, col);

    gather_embed_kernel<<<(N_NODES * (F / 4) + 255) / 256, 256, 0, stream>>>(embed, input_nodes, h_a);

    const int AGG_B  = (N_NODES + 3) / 4;
    const int GEMM_B = (N_NODES + 63) / 64;

    // layer 0: h_a -> h_b
    aggregate_kernel<<<AGG_B, 256, 0, stream>>>(h_a, row_ptr, col, rdeg, meanb);
    gemm_kernel<F, F, true, true><<<GEMM_B, 256, 0, stream>>>(meanb, h_a, Wn0, Ws0, b0, h_b);
    // layer 1: h_b -> h_a
    aggregate_kernel<<<AGG_B, 256, 0, stream>>>(h_b, row_ptr, col, rdeg, meanb);
    gemm_kernel<F, F, true, true><<<GEMM_B, 256, 0, stream>>>(meanb, h_b, Wn1, Ws1, b1, h_a);
    // layer 2: h_a -> out (47 classes, no relu, fp32 out)
    aggregate_kernel<<<AGG_B, 256, 0, stream>>>(h_a, row_ptr, col, rdeg, meanb);
    gemm_kernel<N_CLASSES, 64, false, false><<<GEMM_B, 256, 0, stream>>>(meanb, h_a, Wn2, Ws2, b2, out);
}

// Round 5
// 629.107 us; speedup vs baseline: 2.5999x; 1.2136x over previous
//
#include <hip/hip_runtime.h>

#define N_NODES   100000
#define N_EDGES   1600000
#define F         128
#define N_CLASSES 47
#define SCAN_B    98   // ceil(N_NODES / 1024)

typedef unsigned int uint32;

typedef short  v8s __attribute__((ext_vector_type(8)));   // 8 x bf16 (MFMA A/B frag)
typedef float  v4f __attribute__((ext_vector_type(4)));   // MFMA C/D frag

// bf16 helpers (RNE)
__device__ __forceinline__ uint32 f2bf(float f) {
    uint32 u = __float_as_uint(f);
    return (u + 0x7FFFu + ((u >> 16) & 1u)) >> 16;
}
__device__ __forceinline__ float bfl(uint32 u) { return __uint_as_float(u << 16); }
__device__ __forceinline__ float bfh(uint32 u) { return __uint_as_float(u & 0xFFFF0000u); }

// ---------------- CSR build ----------------

__global__ void count_kernel(const int* __restrict__ dst, int* __restrict__ cnt) {
    int e = blockIdx.x * blockDim.x + threadIdx.x;
    if (e < N_EDGES) atomicAdd(&cnt[dst[e]], 1);
}

__global__ void scan1_kernel(const int* __restrict__ cnt, int* __restrict__ blk_sums) {
    __shared__ int red[1024];
    int t = threadIdx.x;
    int i = blockIdx.x * 1024 + t;
    red[t] = (i < N_NODES) ? cnt[i] : 0;
    __syncthreads();
    #pragma unroll
    for (int off = 512; off > 0; off >>= 1) {
        if (t < off) red[t] += red[t + off];
        __syncthreads();
    }
    if (t == 0) blk_sums[blockIdx.x] = red[0];
}

__global__ void scan2_kernel(int* __restrict__ blk_sums, int* __restrict__ row_ptr) {
    __shared__ int s[128];
    int t = threadIdx.x;
    int v = (t < SCAN_B) ? blk_sums[t] : 0;
    s[t] = v;
    __syncthreads();
    #pragma unroll
    for (int off = 1; off < 128; off <<= 1) {
        int add = (t >= off) ? s[t - off] : 0;
        __syncthreads();
        s[t] += add;
        __syncthreads();
    }
    if (t < SCAN_B) blk_sums[t] = s[t] - v;     // exclusive offset
    if (t == SCAN_B - 1) row_ptr[N_NODES] = s[t];
}

__global__ void scan3_kernel(const int* __restrict__ cnt, const int* __restrict__ blk_offs,
                             int* __restrict__ row_ptr, float* __restrict__ rdeg) {
    __shared__ int s[1024];
    int t = threadIdx.x;
    int i = blockIdx.x * 1024 + t;
    int c = (i < N_NODES) ? cnt[i] : 0;
    s[t] = c;
    __syncthreads();
    #pragma unroll
    for (int off = 1; off < 1024; off <<= 1) {
        int add = (t >= off) ? s[t - off] : 0;
        __syncthreads();
        s[t] += add;
        __syncthreads();
    }
    if (i < N_NODES) {
        row_ptr[i] = s[t] - c + blk_offs[blockIdx.x];
        rdeg[i] = 1.0f / (float)max(c, 1);
    }
}

__global__ void fill_kernel(const int* __restrict__ src, const int* __restrict__ dst,
                            const int* __restrict__ row_ptr, int* __restrict__ fill,
                            int* __restrict__ col) {
    int e = blockIdx.x * blockDim.x + threadIdx.x;
    if (e < N_EDGES) {
        int d = dst[e];
        int p = row_ptr[d] + atomicAdd(&fill[d], 1);
        col[p] = src[e];
    }
}

// ---------------- weight pre-pack: fp32 Wn/Ws -> bf16 MFMA A-frags ----------------
// Wcat[k][m], k in [0,256): k<128 -> Wn[k][m], else Ws[k-128][m].
// A-frag layout (16x16x32): lane L holds A[m = L&15][k = (L>>4)*8 + j], j=0..7.
// Storage: tile = mt*8 + kt; frag at wfrag[(tile*64 + lane)*8 .. +8) (bf16).

__global__ void pack_w_kernel(const float* __restrict__ Wn, const float* __restrict__ Ws,
                              int nout, unsigned short* __restrict__ wfrag) {
    int tile = blockIdx.x;           // mt*8 + kt
    int kt   = tile & 7;
    int mt   = tile >> 3;
    int lane = threadIdx.x;          // 64
    int quad = lane >> 4;
    int m    = mt * 16 + (lane & 15);
    uint32 packed[4];
    #pragma unroll
    for (int jj = 0; jj < 4; ++jj) {
        uint32 lo = 0, hi = 0;
        #pragma unroll
        for (int b = 0; b < 2; ++b) {
            int j = jj * 2 + b;
            int k = kt * 32 + quad * 8 + j;
            float w = 0.f;
            if (m < nout) w = (k < F) ? Wn[(size_t)k * nout + m] : Ws[(size_t)(k - F) * nout + m];
            if (b == 0) lo = f2bf(w); else hi = f2bf(w);
        }
        packed[jj] = lo | (hi << 16);
    }
    uint4 o = make_uint4(packed[0], packed[1], packed[2], packed[3]);
    *(uint4*)(wfrag + ((size_t)tile * 64 + lane) * 8) = o;
}

// ---------------- embedding gather: fp32 embed -> bf16 h ----------------

__global__ void gather_embed_kernel(const float* __restrict__ embed,
                                    const int* __restrict__ idx,
                                    unsigned short* __restrict__ h) {
    int i = blockIdx.x * blockDim.x + threadIdx.x;   // one 4-feat group per thread
    const int TOTAL = N_NODES * (F / 4);
    if (i < TOTAL) {
        int node = i >> 5;
        int c4 = i & 31;
        float4 v = ((const float4*)(embed + (size_t)idx[node] * F))[c4];
        uint2 o;
        o.x = f2bf(v.x) | (f2bf(v.y) << 16);
        o.y = f2bf(v.z) | (f2bf(v.w) << 16);
        ((uint2*)(h + (size_t)node * F))[c4] = o;
    }
}

// ---------------- pull aggregation (bf16 h -> bf16 mean, fp32 accum) ----------------

__global__ void aggregate_kernel(const unsigned short* __restrict__ h,
                                 const int* __restrict__ row_ptr,
                                 const int* __restrict__ col,
                                 const float* __restrict__ rdeg,
                                 unsigned short* __restrict__ mean) {
    int wave = threadIdx.x >> 6;
    int lane = threadIdx.x & 63;
    int v = blockIdx.x * 4 + wave;
    if (v >= N_NODES) return;
    const uint32* hp = (const uint32*)h;   // 64 uints per row
    int beg = row_ptr[v], end = row_ptr[v + 1];
    float ax = 0.f, ay = 0.f;
    int p = beg;
    for (; p + 4 <= end; p += 4) {
        int u0 = col[p], u1 = col[p + 1], u2 = col[p + 2], u3 = col[p + 3];
        uint32 x0 = hp[(size_t)u0 * 64 + lane];
        uint32 x1 = hp[(size_t)u1 * 64 + lane];
        uint32 x2 = hp[(size_t)u2 * 64 + lane];
        uint32 x3 = hp[(size_t)u3 * 64 + lane];
        ax += bfl(x0) + bfl(x1) + bfl(x2) + bfl(x3);
        ay += bfh(x0) + bfh(x1) + bfh(x2) + bfh(x3);
    }
    for (; p < end; ++p) {
        uint32 x = hp[(size_t)col[p] * 64 + lane];
        ax += bfl(x);
        ay += bfh(x);
    }
    float r = rdeg[v];
    ((uint32*)mean)[(size_t)v * 64 + lane] = f2bf(ax * r) | (f2bf(ay * r) << 16);
}

// ---------------- MFMA GEMM: out = [mean|h] @ Wcat + b (+relu) ----------------
// m = out-feature, n = node. A = pre-packed W frags (L1-broadcast), B = node rows
// loaded straight from global (lane reads 16 contiguous bytes). No LDS.
// Block: 4 waves x 32 nodes = 128 nodes. Per wave: MT feat-tiles x 2 node-tiles.

template<int MT, int NOUT, bool RELU, bool OUTBF>
__global__ __launch_bounds__(256)
void mfma_gemm_kernel(const unsigned short* __restrict__ meanb,
                      const unsigned short* __restrict__ h,
                      const unsigned short* __restrict__ wfrag,
                      const float* __restrict__ bias,
                      void* __restrict__ out_) {
    const int lane = threadIdx.x & 63;
    const int wave = threadIdx.x >> 6;
    const int quad = lane >> 4;
    const int nn   = lane & 15;
    const int base = blockIdx.x * 128 + wave * 32;

    const int n0 = base + nn;
    const int n1 = base + 16 + nn;
    const size_t r0 = (size_t)min(n0, N_NODES - 1) * F;   // clamp; store guarded later
    const size_t r1 = (size_t)min(n1, N_NODES - 1) * F;

    v4f acc[MT][2];
    #pragma unroll
    for (int mt = 0; mt < MT; ++mt) { acc[mt][0] = (v4f)0.f; acc[mt][1] = (v4f)0.f; }

    #pragma unroll
    for (int kt = 0; kt < 8; ++kt) {
        const unsigned short* B = (kt < 4) ? meanb : h;
        const int koff = (kt & 3) * 32 + quad * 8;
        v8s b0 = *(const v8s*)(B + r0 + koff);
        v8s b1 = *(const v8s*)(B + r1 + koff);
        #pragma unroll
        for (int mt = 0; mt < MT; ++mt) {
            v8s a = *(const v8s*)(wfrag + ((size_t)(mt * 8 + kt) * 64 + lane) * 8);
            acc[mt][0] = __builtin_amdgcn_mfma_f32_16x16x32_bf16(a, b0, acc[mt][0], 0, 0, 0);
            acc[mt][1] = __builtin_amdgcn_mfma_f32_16x16x32_bf16(a, b1, acc[mt][1], 0, 0, 0);
        }
    }

    // epilogue: C[m = mt*16 + quad*4 + r][n] in acc[mt][nt][r]
    #pragma unroll
    for (int mt = 0; mt < MT; ++mt) {
        const int m0 = mt * 16 + quad * 4;
        #pragma unroll
        for (int nt = 0; nt < 2; ++nt) {
            const int node = base + nt * 16 + nn;
            if (node >= N_NODES) continue;
            v4f a = acc[mt][nt];
            if (OUTBF) {
                const float4 bb = *(const float4*)(bias + m0);
                float x0 = a[0] + bb.x, x1 = a[1] + bb.y, x2 = a[2] + bb.z, x3 = a[3] + bb.w;
                if (RELU) {
                    x0 = fmaxf(x0, 0.f); x1 = fmaxf(x1, 0.f);
                    x2 = fmaxf(x2, 0.f); x3 = fmaxf(x3, 0.f);
                }
                uint2 o;
                o.x = f2bf(x0) | (f2bf(x1) << 16);
                o.y = f2bf(x2) | (f2bf(x3) << 16);
                *(uint2*)((unsigned short*)out_ + (size_t)node * F + m0) = o;
            } else {
                float* out = (float*)out_;
                #pragma unroll
                for (int r = 0; r < 4; ++r) {
                    int m = m0 + r;
                    if (m < NOUT) {
                        float v = a[r] + bias[m];
                        if (RELU) v = fmaxf(v, 0.f);
                        out[(size_t)node * NOUT + m] = v;
                    }
                }
            }
        }
    }
}

// ---------------- launch ----------------

extern "C" void kernel_launch(void* const* d_in, const int* in_sizes, int n_in,
                              void* d_out, int out_size, void* d_ws, size_t ws_size,
                              hipStream_t stream) {
    const float* embed = (const float*)d_in[0];
    const float* Ws0   = (const float*)d_in[1];
    const float* Wn0   = (const float*)d_in[2];
    const float* b0    = (const float*)d_in[3];
    const float* Ws1   = (const float*)d_in[4];
    const float* Wn1   = (const float*)d_in[5];
    const float* b1    = (const float*)d_in[6];
    const float* Ws2   = (const float*)d_in[7];
    const float* Wn2   = (const float*)d_in[8];
    const float* b2    = (const float*)d_in[9];
    const int* input_nodes = (const int*)d_in[10];
    const int* src     = (const int*)d_in[11];
    const int* dst     = (const int*)d_in[12];
    float* out = (float*)d_out;

    char* ws = (char*)d_ws;
    size_t off = 0;
    auto alloc = [&](size_t bytes) -> void* {
        void* p = ws + off;
        off += (bytes + 255) & ~(size_t)255;
        return p;
    };
    int*            cnt      = (int*)           alloc(sizeof(int)   * N_NODES);
    int*            fill     = (int*)           alloc(sizeof(int)   * N_NODES);
    int*            row_ptr  = (int*)           alloc(sizeof(int)   * (N_NODES + 1));
    float*          rdeg     = (float*)         alloc(sizeof(float) * N_NODES);
    int*            col      = (int*)           alloc(sizeof(int)   * N_EDGES);
    int*            blk_sums = (int*)           alloc(sizeof(int)   * 128);
    unsigned short* h_a      = (unsigned short*)alloc(2 * (size_t)N_NODES * F);
    unsigned short* h_b      = (unsigned short*)alloc(2 * (size_t)N_NODES * F);
    unsigned short* meanb    = (unsigned short*)alloc(2 * (size_t)N_NODES * F);
    unsigned short* wf0      = (unsigned short*)alloc(2 * 64 * 512);   // 8mt x 8kt x 64 x 8
    unsigned short* wf1      = (unsigned short*)alloc(2 * 64 * 512);
    unsigned short* wf2      = (unsigned short*)alloc(2 * 24 * 512);   // 3mt x 8kt
    (void)ws_size; (void)n_in; (void)in_sizes; (void)out_size;

    hipMemsetAsync(cnt,  0, sizeof(int) * N_NODES, stream);
    hipMemsetAsync(fill, 0, sizeof(int) * N_NODES, stream);

    const int EB = (N_EDGES + 255) / 256;
    count_kernel<<<EB, 256, 0, stream>>>(dst, cnt);
    scan1_kernel<<<SCAN_B, 1024, 0, stream>>>(cnt, blk_sums);
    scan2_kernel<<<1, 128, 0, stream>>>(blk_sums, row_ptr);
    scan3_kernel<<<SCAN_B, 1024, 0, stream>>>(cnt, blk_sums, row_ptr, rdeg);
    fill_kernel<<<EB, 256, 0, stream>>>(src, dst, row_ptr, fill, col);

    pack_w_kernel<<<64, 64, 0, stream>>>(Wn0, Ws0, F, wf0);
    pack_w_kernel<<<64, 64, 0, stream>>>(Wn1, Ws1, F, wf1);
    pack_w_kernel<<<24, 64, 0, stream>>>(Wn2, Ws2, N_CLASSES, wf2);

    gather_embed_kernel<<<(N_NODES * (F / 4) + 255) / 256, 256, 0, stream>>>(embed, input_nodes, h_a);

    const int AGG_B  = (N_NODES + 3) / 4;
    const int GEMM_B = (N_NODES + 127) / 128;

    // layer 0: h_a -> h_b
    aggregate_kernel<<<AGG_B, 256, 0, stream>>>(h_a, row_ptr, col, rdeg, meanb);
    mfma_gemm_kernel<8, F, true, true><<<GEMM_B, 256, 0, stream>>>(meanb, h_a, wf0, b0, h_b);
    // layer 1: h_b -> h_a
    aggregate_kernel<<<AGG_B, 256, 0, stream>>>(h_b, row_ptr, col, rdeg, meanb);
    mfma_gemm_kernel<8, F, true, true><<<GEMM_B, 256, 0, stream>>>(meanb, h_b, wf1, b1, h_a);
    // layer 2: h_a -> out (47 classes, no relu, fp32 out)
    aggregate_kernel<<<AGG_B, 256, 0, stream>>>(h_a, row_ptr, col, rdeg, meanb);
    mfma_gemm_kernel<3, N_CLASSES, false, false><<<GEMM_B, 256, 0, stream>>>(meanb, h_a, wf2, b2, out);
}